// Round 1
// baseline (254.862 us; speedup 1.0000x reference)
//
#include <hip/hip_runtime.h>

#define NTHREADS 256
#define HALF 256
#define ROWLEN 257   // 256 fts + 1 psqt
#define MAX_FTS 30

__global__ __launch_bounds__(NTHREADS) void nnue_fwd(
    const int* __restrict__ wft,
    const int* __restrict__ bft,
    const float* __restrict__ stm,
    const float* __restrict__ ft_w,
    const float* __restrict__ ft_b,
    const float* __restrict__ fc1_w,
    const float* __restrict__ fc1_b,
    const float* __restrict__ fc2_w,
    const float* __restrict__ fc2_b,
    const float* __restrict__ fco_w,
    const float* __restrict__ fco_b,
    float* __restrict__ out)
{
    const int s = blockIdx.x;
    const int t = threadIdx.x;

    __shared__ int   s_iw[MAX_FTS];
    __shared__ int   s_ib[MAX_FTS];
    __shared__ float s_x[2 * HALF];
    __shared__ float s_h1[32];
    __shared__ float s_h2[32];
    __shared__ float s_ps[2];

    if (t < MAX_FTS)                      s_iw[t]      = wft[s * MAX_FTS + t];
    else if (t >= 64 && t < 64 + MAX_FTS) s_ib[t - 64] = bft[s * MAX_FTS + (t - 64)];
    __syncthreads();

    // ---- feature transform: thread t accumulates element t of both halves ----
    float accw = ft_b[t];
    float accb = ft_b[t];

#pragma unroll
    for (int i = 0; i < MAX_FTS; ++i) {
        int icw = __builtin_amdgcn_readfirstlane(s_iw[i]);
        int icb = __builtin_amdgcn_readfirstlane(s_ib[i]);
        float mw = icw >= 0 ? 1.0f : 0.0f;
        float mb = icb >= 0 ? 1.0f : 0.0f;
        int ow = (icw >= 0 ? icw : 0) * ROWLEN;
        int ob = (icb >= 0 ? icb : 0) * ROWLEN;
        accw = fmaf(ft_w[ow + t], mw, accw);
        accb = fmaf(ft_w[ob + t], mb, accb);
    }

    // ---- psqt column (element 256): one lane per perspective ----
    if (t == 0 || t == 64) {
        const int* idx = (t == 0) ? s_iw : s_ib;
        float ps = 0.0f;
#pragma unroll
        for (int i = 0; i < MAX_FTS; ++i) {
            int ic = idx[i];
            float m = ic >= 0 ? 1.0f : 0.0f;
            int o = (ic >= 0 ? ic : 0) * ROWLEN;
            ps = fmaf(ft_w[o + HALF], m, ps);
        }
        s_ps[t == 0 ? 0 : 1] = ps;
    }

    // ---- stm select/lerp + clip, stage x[512] to LDS ----
    const float st = stm[s];
    float xl = (1.0f - st) * accw + st * accb;
    float xh = (1.0f - st) * accb + st * accw;
    s_x[t]        = fminf(fmaxf(xl, 0.0f), 1.0f);
    s_x[t + HALF] = fminf(fmaxf(xh, 0.0f), 1.0f);
    __syncthreads();

    // ---- FC1: 32 outputs, 8 lanes each (j = t>>3, p = t&7), 64 FMAs/lane ----
    const int j = t >> 3, p = t & 7;
    const float* w1 = fc1_w + j * (2 * HALF);
    float part = 0.0f;
#pragma unroll
    for (int i = 0; i < 64; ++i) {
        int k = (i << 3) | p;                 // 8 consecutive banks, broadcast across j
        part = fmaf(s_x[k], w1[k], part);
    }
    part += __shfl_xor(part, 1, 64);
    part += __shfl_xor(part, 2, 64);
    part += __shfl_xor(part, 4, 64);
    if (p == 0) s_h1[j] = fminf(fmaxf(part + fc1_b[j], 0.0f), 1.0f);
    __syncthreads();

    // ---- FC2: 32x32 on 32 threads ----
    if (t < 32) {
        float a = fc2_b[t];
        const float* w2 = fc2_w + t * 32;
#pragma unroll
        for (int k = 0; k < 32; ++k) a = fmaf(s_h1[k], w2[k], a);
        s_h2[t] = fminf(fmaxf(a, 0.0f), 1.0f);
    }
    __syncthreads();

    // ---- FCO + psqt term ----
    if (t == 0) {
        float o = fco_b[0];
#pragma unroll
        for (int k = 0; k < 32; ++k) o = fmaf(s_h2[k], fco_w[k], o);
        o += (s_ps[0] - s_ps[1]) * (0.5f - st);
        out[s] = o;
    }
}

extern "C" void kernel_launch(void* const* d_in, const int* in_sizes, int n_in,
                              void* d_out, int out_size, void* d_ws, size_t ws_size,
                              hipStream_t stream) {
    const int*   wft   = (const int*)  d_in[0];
    const int*   bft   = (const int*)  d_in[1];
    const float* stm   = (const float*)d_in[2];
    const float* ft_w  = (const float*)d_in[3];
    const float* ft_b  = (const float*)d_in[4];
    const float* fc1_w = (const float*)d_in[5];
    const float* fc1_b = (const float*)d_in[6];
    const float* fc2_w = (const float*)d_in[7];
    const float* fc2_b = (const float*)d_in[8];
    const float* fco_w = (const float*)d_in[9];
    const float* fco_b = (const float*)d_in[10];
    float* out = (float*)d_out;

    const int B = in_sizes[0] / MAX_FTS;
    nnue_fwd<<<B, NTHREADS, 0, stream>>>(wft, bft, stm, ft_w, ft_b,
                                         fc1_w, fc1_b, fc2_w, fc2_b,
                                         fco_w, fco_b, out);
}

// Round 2
// 139.908 us; speedup vs baseline: 1.8216x; 1.8216x over previous
//
#include <hip/hip_runtime.h>

#define NTHREADS 256
#define HALF 256
#define ROWLEN 257    // 256 fts + 1 psqt
#define MAX_FTS 30
#define PAD_STRIDE 264  // halves per row in converted fp16 table (528 B, 16B-aligned)

typedef __attribute__((ext_vector_type(4))) float f32x4;
typedef __attribute__((ext_vector_type(8))) _Float16 f16x8;

// ---------------------------------------------------------------------------
// Pass 0: ft_w (N_FTS x 257 f32) -> fp16 table (stride 264) + f32 psqt column
// ---------------------------------------------------------------------------
__global__ __launch_bounds__(256) void convert_tbl(
    const float* __restrict__ ft_w,
    _Float16* __restrict__ tbl,
    float* __restrict__ psq,
    int total)
{
    for (int i = blockIdx.x * 256 + threadIdx.x; i < total; i += gridDim.x * 256) {
        int r = i / ROWLEN;
        int e = i - r * ROWLEN;
        float v = ft_w[i];
        if (e < HALF) tbl[r * PAD_STRIDE + e] = (_Float16)v;
        else          psq[r] = v;
    }
}

// ---------------------------------------------------------------------------
// Main kernel: one block per sample. FT: half-wave q (=wave*2+halfwave) owns
// row slots {q, q+8, q+16, q+24}; lane covers 8 elements via one 16B fp16 load
// per row. Partials reduced across the 8 half-waves through LDS, then the
// FC pipeline (identical to the verified R1 version).
// ---------------------------------------------------------------------------
__global__ __launch_bounds__(NTHREADS) void nnue_fwd_h(
    const int* __restrict__ wft,
    const int* __restrict__ bft,
    const float* __restrict__ stm,
    const _Float16* __restrict__ tbl,
    const float* __restrict__ psq,
    const float* __restrict__ ft_b,
    const float* __restrict__ fc1_w,
    const float* __restrict__ fc1_b,
    const float* __restrict__ fc2_w,
    const float* __restrict__ fc2_b,
    const float* __restrict__ fco_w,
    const float* __restrict__ fco_b,
    float* __restrict__ out)
{
    const int s = blockIdx.x;
    const int t = threadIdx.x;
    const int w = t >> 6;        // wave 0..3
    const int l = t & 63;        // lane
    const int h = l >> 5;        // half-wave
    const int c = l & 31;        // lane-in-half-wave: elements c*8 .. c*8+7
    const int q = (w << 1) | h;  // partial slot 0..7

    __shared__ int   s_iw[MAX_FTS];
    __shared__ int   s_ib[MAX_FTS];
    __shared__ float s_part[8][2][HALF];   // 16 KB
    __shared__ float s_x[2 * HALF];
    __shared__ float s_h1[32];
    __shared__ float s_h2[32];
    __shared__ float s_ps;

    if (t < MAX_FTS)                      s_iw[t]      = wft[s * MAX_FTS + t];
    else if (t >= 64 && t < 64 + MAX_FTS) s_ib[t - 64] = bft[s * MAX_FTS + (t - 64)];
    __syncthreads();

    // ---- feature transform partials (fp16 gathers, 16B per lane per row) ----
    float aw[8], ab[8];
#pragma unroll
    for (int k = 0; k < 8; ++k) { aw[k] = 0.0f; ab[k] = 0.0f; }

#pragma unroll
    for (int i = 0; i < 4; ++i) {
        const int r = (i << 3) + q;
        if (r < MAX_FTS) {
            const int icw = s_iw[r];
            if (icw >= 0) {
                const f16x8 v = *reinterpret_cast<const f16x8*>(tbl + (size_t)icw * PAD_STRIDE + (c << 3));
#pragma unroll
                for (int k = 0; k < 8; ++k) aw[k] += (float)v[k];
            }
            const int icb = s_ib[r];
            if (icb >= 0) {
                const f16x8 v = *reinterpret_cast<const f16x8*>(tbl + (size_t)icb * PAD_STRIDE + (c << 3));
#pragma unroll
                for (int k = 0; k < 8; ++k) ab[k] += (float)v[k];
            }
        }
    }

    {
        f32x4 v0 = {aw[0], aw[1], aw[2], aw[3]};
        f32x4 v1 = {aw[4], aw[5], aw[6], aw[7]};
        f32x4 v2 = {ab[0], ab[1], ab[2], ab[3]};
        f32x4 v3 = {ab[4], ab[5], ab[6], ab[7]};
        *reinterpret_cast<f32x4*>(&s_part[q][0][(c << 3)])     = v0;
        *reinterpret_cast<f32x4*>(&s_part[q][0][(c << 3) + 4]) = v1;
        *reinterpret_cast<f32x4*>(&s_part[q][1][(c << 3)])     = v2;
        *reinterpret_cast<f32x4*>(&s_part[q][1][(c << 3) + 4]) = v3;
    }

    // ---- psqt diff on wave 0 (f32 column, exact path), butterfly reduce ----
    if (w == 0) {
        float pv = 0.0f;
        if (l < MAX_FTS) {
            int ic = s_iw[l];
            if (ic >= 0) pv = psq[ic];
        } else if (l >= 32 && l < 32 + MAX_FTS) {
            int ic = s_ib[l - 32];
            if (ic >= 0) pv = -psq[ic];
        }
        pv += __shfl_xor(pv, 1, 64);
        pv += __shfl_xor(pv, 2, 64);
        pv += __shfl_xor(pv, 4, 64);
        pv += __shfl_xor(pv, 8, 64);
        pv += __shfl_xor(pv, 16, 64);
        pv += __shfl_xor(pv, 32, 64);
        if (l == 0) s_ps = pv;
    }
    __syncthreads();

    // ---- sum the 8 partials: thread t owns element t ----
    float accw = ft_b[t];
    float accb = ft_b[t];
#pragma unroll
    for (int qq = 0; qq < 8; ++qq) {
        accw += s_part[qq][0][t];
        accb += s_part[qq][1][t];
    }

    // ---- stm select/lerp + clip ----
    const float st = stm[s];
    float xl = (1.0f - st) * accw + st * accb;
    float xh = (1.0f - st) * accb + st * accw;
    s_x[t]        = fminf(fmaxf(xl, 0.0f), 1.0f);
    s_x[t + HALF] = fminf(fmaxf(xh, 0.0f), 1.0f);
    __syncthreads();

    // ---- FC1: 32 outputs, 8 lanes each ----
    const int j = t >> 3, p = t & 7;
    const float* w1 = fc1_w + j * (2 * HALF);
    float part = 0.0f;
#pragma unroll
    for (int i = 0; i < 64; ++i) {
        int k = (i << 3) | p;
        part = fmaf(s_x[k], w1[k], part);
    }
    part += __shfl_xor(part, 1, 64);
    part += __shfl_xor(part, 2, 64);
    part += __shfl_xor(part, 4, 64);
    if (p == 0) s_h1[j] = fminf(fmaxf(part + fc1_b[j], 0.0f), 1.0f);
    __syncthreads();

    // ---- FC2 ----
    if (t < 32) {
        float a = fc2_b[t];
        const float* w2 = fc2_w + t * 32;
#pragma unroll
        for (int k = 0; k < 32; ++k) a = fmaf(s_h1[k], w2[k], a);
        s_h2[t] = fminf(fmaxf(a, 0.0f), 1.0f);
    }
    __syncthreads();

    // ---- FCO + psqt term ----
    if (t == 0) {
        float o = fco_b[0];
#pragma unroll
        for (int k = 0; k < 32; ++k) o = fmaf(s_h2[k], fco_w[k], o);
        o += s_ps * (0.5f - st);
        out[s] = o;
    }
}

// ---------------------------------------------------------------------------
// Fallback (verified R1 f32 kernel) — used only if ws is too small.
// ---------------------------------------------------------------------------
__global__ __launch_bounds__(NTHREADS) void nnue_fwd(
    const int* __restrict__ wft,
    const int* __restrict__ bft,
    const float* __restrict__ stm,
    const float* __restrict__ ft_w,
    const float* __restrict__ ft_b,
    const float* __restrict__ fc1_w,
    const float* __restrict__ fc1_b,
    const float* __restrict__ fc2_w,
    const float* __restrict__ fc2_b,
    const float* __restrict__ fco_w,
    const float* __restrict__ fco_b,
    float* __restrict__ out)
{
    const int s = blockIdx.x;
    const int t = threadIdx.x;

    __shared__ int   s_iw[MAX_FTS];
    __shared__ int   s_ib[MAX_FTS];
    __shared__ float s_x[2 * HALF];
    __shared__ float s_h1[32];
    __shared__ float s_h2[32];
    __shared__ float s_ps[2];

    if (t < MAX_FTS)                      s_iw[t]      = wft[s * MAX_FTS + t];
    else if (t >= 64 && t < 64 + MAX_FTS) s_ib[t - 64] = bft[s * MAX_FTS + (t - 64)];
    __syncthreads();

    float accw = ft_b[t];
    float accb = ft_b[t];
#pragma unroll
    for (int i = 0; i < MAX_FTS; ++i) {
        int icw = __builtin_amdgcn_readfirstlane(s_iw[i]);
        int icb = __builtin_amdgcn_readfirstlane(s_ib[i]);
        float mw = icw >= 0 ? 1.0f : 0.0f;
        float mb = icb >= 0 ? 1.0f : 0.0f;
        int ow = (icw >= 0 ? icw : 0) * ROWLEN;
        int ob = (icb >= 0 ? icb : 0) * ROWLEN;
        accw = fmaf(ft_w[ow + t], mw, accw);
        accb = fmaf(ft_w[ob + t], mb, accb);
    }

    if (t == 0 || t == 64) {
        const int* idx = (t == 0) ? s_iw : s_ib;
        float ps = 0.0f;
#pragma unroll
        for (int i = 0; i < MAX_FTS; ++i) {
            int ic = idx[i];
            float m = ic >= 0 ? 1.0f : 0.0f;
            int o = (ic >= 0 ? ic : 0) * ROWLEN;
            ps = fmaf(ft_w[o + HALF], m, ps);
        }
        s_ps[t == 0 ? 0 : 1] = ps;
    }

    const float st = stm[s];
    float xl = (1.0f - st) * accw + st * accb;
    float xh = (1.0f - st) * accb + st * accw;
    s_x[t]        = fminf(fmaxf(xl, 0.0f), 1.0f);
    s_x[t + HALF] = fminf(fmaxf(xh, 0.0f), 1.0f);
    __syncthreads();

    const int j = t >> 3, p = t & 7;
    const float* w1 = fc1_w + j * (2 * HALF);
    float part = 0.0f;
#pragma unroll
    for (int i = 0; i < 64; ++i) {
        int k = (i << 3) | p;
        part = fmaf(s_x[k], w1[k], part);
    }
    part += __shfl_xor(part, 1, 64);
    part += __shfl_xor(part, 2, 64);
    part += __shfl_xor(part, 4, 64);
    if (p == 0) s_h1[j] = fminf(fmaxf(part + fc1_b[j], 0.0f), 1.0f);
    __syncthreads();

    if (t < 32) {
        float a = fc2_b[t];
        const float* w2 = fc2_w + t * 32;
#pragma unroll
        for (int k = 0; k < 32; ++k) a = fmaf(s_h1[k], w2[k], a);
        s_h2[t] = fminf(fmaxf(a, 0.0f), 1.0f);
    }
    __syncthreads();

    if (t == 0) {
        float o = fco_b[0];
#pragma unroll
        for (int k = 0; k < 32; ++k) o = fmaf(s_h2[k], fco_w[k], o);
        o += (s_ps[0] - s_ps[1]) * (0.5f - st);
        out[s] = o;
    }
}

extern "C" void kernel_launch(void* const* d_in, const int* in_sizes, int n_in,
                              void* d_out, int out_size, void* d_ws, size_t ws_size,
                              hipStream_t stream) {
    const int*   wft   = (const int*)  d_in[0];
    const int*   bft   = (const int*)  d_in[1];
    const float* stm   = (const float*)d_in[2];
    const float* ft_w  = (const float*)d_in[3];
    const float* ft_b  = (const float*)d_in[4];
    const float* fc1_w = (const float*)d_in[5];
    const float* fc1_b = (const float*)d_in[6];
    const float* fc2_w = (const float*)d_in[7];
    const float* fc2_b = (const float*)d_in[8];
    const float* fco_w = (const float*)d_in[9];
    const float* fco_b = (const float*)d_in[10];
    float* out = (float*)d_out;

    const int B     = in_sizes[0] / MAX_FTS;
    const int n_fts = in_sizes[3] / ROWLEN;

    const size_t psq_bytes = (size_t)n_fts * sizeof(float);
    const size_t tbl_bytes = (size_t)n_fts * PAD_STRIDE * sizeof(_Float16);
    const size_t need = psq_bytes + tbl_bytes;

    if (ws_size >= need) {
        float*    psq = (float*)d_ws;
        _Float16* tbl = (_Float16*)((char*)d_ws + psq_bytes);
        convert_tbl<<<4096, 256, 0, stream>>>(ft_w, tbl, psq, n_fts * ROWLEN);
        nnue_fwd_h<<<B, NTHREADS, 0, stream>>>(wft, bft, stm, tbl, psq, ft_b,
                                               fc1_w, fc1_b, fc2_w, fc2_b,
                                               fco_w, fco_b, out);
    } else {
        nnue_fwd<<<B, NTHREADS, 0, stream>>>(wft, bft, stm, ft_w, ft_b,
                                             fc1_w, fc1_b, fc2_w, fc2_b,
                                             fco_w, fco_b, out);
    }
}